// Round 14
// baseline (590.395 us; speedup 1.0000x reference)
//
#include <hip/hip_runtime.h>

#define Bq 8
#define Fq 16
#define Nq 1024
#define Eq 256
#define Tq 64
constexpr float ALPHAq = 0.2f;
constexpr float LOG2Eq = 1.4426950408889634f;
constexpr int NNZCAP = 32768;       // global CSR allocation cap (actual nnz ~13.4K)
constexpr int MAXJE  = 20;          // edge-side entries/thread in regs (deg<=80); tail covers rest
constexpr int NNZW2  = 20480;       // padded node-major wvl data slots (actual ~15K)
constexpr int DUMP0  = NNZW2;       // 1024 dump slots for sentinel writes
constexpr int WVLTOT = NNZW2 + 1024;

// quad-lane exchanges on the VALU pipe (DPP), replacing ds_bpermute shuffles.
// quad_perm [1,0,3,2] = 0xB1 (lane^1), [2,3,0,1] = 0x4E (lane^2).
__device__ __forceinline__ float qswap1(float x) {
  return __int_as_float(__builtin_amdgcn_mov_dpp(__float_as_int(x), 0xB1, 0xF, 0xF, true));
}
__device__ __forceinline__ float qswap2(float x) {
  return __int_as_float(__builtin_amdgcn_mov_dpp(__float_as_int(x), 0x4E, 0xF, 0xF, true));
}

// ---------- counts: edge counts per rowblock + node counts ----------
__global__ __launch_bounds__(256) void k_cntB(const float* __restrict__ inc,
                                              int* __restrict__ gcnt,
                                              int* __restrict__ ncnt) {
  const int i = blockIdx.x, e = threadIdx.x;
  const int base = i * 64;
  int c = 0;
  for (int r = 0; r < 64; ++r) c += (inc[(size_t)(base + r) * Eq + e] > 0.f) ? 1 : 0;
  gcnt[i * Eq + e] = c;
  if (i < 4) {
    const int n = i * 256 + e;
    const float* row = inc + (size_t)n * Eq;
    int cn = 0;
    for (int k = 0; k < Eq; ++k) cn += (row[k] > 0.f) ? 1 : 0;
    ncnt[n] = cn;
  }
}

// ---------- prefixes: edge CSR ptr + rowblock offsets + node CSR (plain & padded) ----------
__global__ __launch_bounds__(1024) void k_prefB(const int* __restrict__ gcnt,
                                                const int* __restrict__ ncnt,
                                                int* __restrict__ g_ptr,
                                                int* __restrict__ goff,
                                                int* __restrict__ tlp,
                                                int* __restrict__ tlp2) {
  __shared__ int tot[Eq];
  __shared__ int sptr[Eq + 1];
  __shared__ int sn[Nq];
  __shared__ int snp[Nq + 1];
  __shared__ int snp2[Nq + 1];
  const int tid = threadIdx.x;
  if (tid < Eq) { int s = 0; for (int i = 0; i < 16; ++i) s += gcnt[i * Eq + tid]; tot[tid] = s; }
  sn[tid] = ncnt[tid];
  __syncthreads();
  if (tid == 0) { int s = 0; for (int j = 0; j < Eq; ++j) { sptr[j] = s; s += tot[j]; } sptr[Eq] = s; }
  if (tid == 1) { int s = 0; for (int i = 0; i < Nq; ++i) { snp[i] = s; s += sn[i]; } snp[Nq] = s; }
  if (tid == 2) { int s = 0; for (int i = 0; i < Nq; ++i) { snp2[i] = s; s += (sn[i] + 3) & ~3; } snp2[Nq] = s; }
  __syncthreads();
  if (tid <= Eq) g_ptr[tid] = sptr[tid];
  tlp[tid] = snp[tid];
  tlp2[tid] = snp2[tid];
  if (tid == 0) { tlp[Nq] = snp[Nq]; tlp2[Nq] = snp2[Nq]; }
  if (tid < Eq) {
    int run = sptr[tid];
    for (int i = 0; i < 16; ++i) { goff[i * Eq + tid] = run; run += gcnt[i * Eq + tid]; }
  }
}

// ---------- fills: edge-CSR node list + node-CSR edge list ----------
__global__ __launch_bounds__(256) void k_fillB(const float* __restrict__ inc,
                                               const int* __restrict__ goff,
                                               const int* __restrict__ tlp,
                                               unsigned short* __restrict__ g_nodes,
                                               unsigned short* __restrict__ tle_g) {
  const int i = blockIdx.x, e = threadIdx.x;
  const int base = i * 64;
  int w = goff[i * Eq + e];
  for (int r = 0; r < 64; ++r) {
    const int n = base + r;
    if (inc[(size_t)n * Eq + e] > 0.f) { if (w < NNZCAP) g_nodes[w] = (unsigned short)n; ++w; }
  }
  if (i < 4) {
    const int n = i * 256 + e;
    const float* row = inc + (size_t)n * Eq;
    int wn = tlp[n];
    for (int k = 0; k < Eq; ++k)
      if (row[k] > 0.f) { if (wn < NNZCAP) tle_g[wn] = (unsigned short)k; ++wn; }
  }
}

// ---------- prep: packed (wpos2<<16 | n) per-thread table + padded wpos map ----------
__global__ __launch_bounds__(256) void k_prep(const int* __restrict__ g_ptr,
                                              const unsigned short* __restrict__ g_nodes,
                                              const int* __restrict__ tlp_g,
                                              const int* __restrict__ tlp2_g,
                                              const unsigned short* __restrict__ tle_g,
                                              unsigned* __restrict__ tbl_g,
                                              unsigned short* __restrict__ wpos_g) {
  const int t = blockIdx.x * 256 + threadIdx.x;   // 0..1023 (e = t>>2, sub = t&3)
  const int e = t >> 2, sub = t & 3;
  const int p0 = g_ptr[e], p1 = g_ptr[e + 1];
  int j = 0;
  for (int pos = p0 + sub; pos < p1; pos += 4, ++j) {
    const int n = (int)g_nodes[pos];
    int lo = tlp_g[n], hi = tlp_g[n + 1];
    while (lo < hi) { int mid = (lo + hi) >> 1; if ((int)tle_g[mid] < e) lo = mid + 1; else hi = mid; }
    int wp = tlp2_g[n] + (lo - tlp_g[n]);          // padded node-major slot
    if (wp >= NNZW2) wp = DUMP0 + t;               // defensive clamp
    wpos_g[pos] = (unsigned short)wp;
    if (j < MAXJE) tbl_g[j * Nq + t] = ((unsigned)wp << 16) | (unsigned)n;
  }
  for (; j < MAXJE; ++j)
    tbl_g[j * Nq + t] = ((unsigned)(DUMP0 + t) << 16) | (unsigned)Nq;   // sentinel
}

// ---------- static node projection for all timesteps ----------
__global__ __launch_bounds__(256) void k_xnp(const float* __restrict__ x,
                                             const float* __restrict__ mask,
                                             const float* __restrict__ weight,
                                             const float* __restrict__ bias,
                                             float* __restrict__ xnpT) {
  __shared__ float accs[64][65];
  const int wg = blockIdx.x;
  const int b = wg >> 4;
  const int n0 = (wg & 15) << 6;
  const int lane = threadIdx.x & 63;
  const int w = threadIdx.x >> 6;
  float a[16];
#pragma unroll
  for (int i = 0; i < 16; ++i) a[i] = 0.f;
  for (int f = 0; f < Fq; ++f) {
    const float wf = weight[f], wm = weight[Fq + f];
#pragma unroll
    for (int ii = 0; ii < 16; ++ii) {
      const int i = w + ii * 4;
      const size_t base = ((size_t)(b * Fq + f) * Nq + n0 + i) * Tq + lane;
      a[ii] += x[base] * wf + mask[base] * wm;
    }
  }
#pragma unroll
  for (int ii = 0; ii < 16; ++ii) accs[w + ii * 4][lane] = a[ii];
  __syncthreads();
  const float bl = bias[n0 + lane];
#pragma unroll
  for (int jj = 0; jj < 16; ++jj) {
    const int tt = w + jj * 4;
    xnpT[((size_t)b * Tq + tt) * Nq + n0 + lane] = accs[lane][tt] + bl;
  }
}

// ---------- full 64-step recurrence: one block per batch ----------
// Round-12 structure (no sort, no per-iteration guards: LDS reads issue batched
// so their latency overlaps -- round 13 proved guards break this). New: exp
// computed in base-2 domain with log2e folded into the CONSTANTS (a0L, e2a1L),
// deleting the per-entry v_mul that __expf emits. Correlated rounding preserved:
// s2 and sm2 are the same expression, so max-entry arg == 0 exactly, all <= 0.
__global__ __attribute__((amdgpu_flat_work_group_size(1024, 1024), amdgpu_waves_per_eu(4, 4)))
void k_recur(
    const float* __restrict__ xnpT, const float* __restrict__ w2,
    const int* __restrict__ g_ptr, const unsigned short* __restrict__ g_nodes,
    const unsigned short* __restrict__ wpos_g,
    const int* __restrict__ tlp_g, const int* __restrict__ tlp2_g,
    const unsigned* __restrict__ tbl_g,
    const float* __restrict__ h0,
    const float* __restrict__ weight, const float* __restrict__ a_vec,
    float* __restrict__ out) {
  __shared__ __align__(16) float wvl[WVLTOT];   // 86KB padded node-major attn*edge (+dump)
  __shared__ float xnl[Nq + 4];                 // xn this step; [1024] = 0 sentinel
  __shared__ __align__(16) float epp[4 * 72];   // edge_pre, bank-padded (stride 72)

  const int b = blockIdx.x;
  const int tid = threadIdx.x;
  const int e = tid >> 2;                       // 256 edges, 4 threads each
  const int sub = tid & 3;
  const float w32 = weight[2 * Fq];
  const float a0 = a_vec[0], a1 = a_vec[1];
  const float a0L = a0 * LOG2Eq;                // base-2-domain slope

  // ---- zero wvl once (pads stay 0 forever; real slots rewritten every step) ----
  for (int i = tid; i < WVLTOT; i += 1024) wvl[i] = 0.f;

  float xn_reg = xnpT[(size_t)b * Tq * Nq + tid] + w32 * h0[tid];
  xnl[tid] = xn_reg;
  if (tid == 0) xnl[Nq] = 0.f;                  // pass1 sentinel

  // ---- constant per-thread index table in registers ----
  unsigned uj[MAXJE];
#pragma unroll
  for (int j = 0; j < MAXJE; ++j) uj[j] = tbl_g[j * Nq + tid];

  // ---- w2 column slice in registers: w2r[kk] = w2[sub*64+kk][e] ----
  float w2r[64];
#pragma unroll
  for (int kk = 0; kk < 64; ++kk)
    w2r[kk] = w2[(size_t)(sub * 64 + kk) * Eq + e];

  const int p0 = g_ptr[e], p1 = g_ptr[e + 1];
  const float degf = (float)(p1 - p0);
  const int tail0 = p0 + sub + 4 * MAXJE;       // edge-side tail start (deg>80 only)
  const int q0v = tlp2_g[tid] >> 2;             // my node's first float4 slot
  const int degn = tlp_g[tid + 1] - tlp_g[tid];
  const int iters = (tid == 0) ? 0 : ((degn + 3) >> 2);   // node0 via wave-0 reduce
  __syncthreads();                              // xnl + wvl zeros ready

  float xv[MAXJE];

  for (int t = 0; t < Tq; ++t) {
    // prefetch next xnp row value for my node
    const float xnext = xnpT[((size_t)b * Tq + (t + 1 < Tq ? t + 1 : t)) * Nq + tid];

    // ---- pass1: gather incident xn; edge_pre partial; running max (monotonicity) ----
    float v = 0.f;
    float mxv = -3.0e38f;
#pragma unroll
    for (int j = 0; j < MAXJE; ++j) {
      const int n = (int)(uj[j] & 0xffffu);
      const float xx = xnl[n];                  // sentinel n=1024 -> 0
      v += xx;
      const float val = (n < Nq) ? xx : -1.0e30f;
      xv[j] = val;
      mxv = fmaxf(mxv, val);
    }
    for (int pos = tail0; pos < p1; pos += 4) {
      const float xx = xnl[(int)g_nodes[pos]];
      v += xx;
      mxv = fmaxf(mxv, xx);
    }
    v += qswap1(v);
    v += qswap2(v);
    mxv = fmaxf(mxv, qswap1(mxv));
    mxv = fmaxf(mxv, qswap2(mxv));
    if (sub == 0) epp[(e >> 6) * 72 + (e & 63)] = v / degf;
    __syncthreads();  // S1: ep complete

    // ---- mat-vec: edge2 = ep @ w2 (register w2, bank-padded b128 ep reads) ----
    float acc = 0.f;
#pragma unroll
    for (int k = 0; k < 16; ++k) {
      const float4 epv = *reinterpret_cast<const float4*>(&epp[sub * 72 + (k << 2)]);
      acc += w2r[k * 4 + 0] * epv.x + w2r[k * 4 + 1] * epv.y +
             w2r[k * 4 + 2] * epv.z + w2r[k * 4 + 3] * epv.w;
    }
    acc += qswap1(acc);
    acc += qswap2(acc);
    const float edge2 = acc;                    // time_e cancels in the softmax ratio
    // base-2 domain: everything scaled by log2e via the constants
    const float e2a1L = (edge2 * a1) * LOG2Eq;
    // max via monotonicity; SAME expression shape as per-entry s2
    const float sm2 = mxv * a0L + e2a1L;
    const float mx2 = fmaxf(sm2, ALPHAq * sm2);

    // ---- Z; overwrite xv with exp2 (correlated rounding: arg <= 0 in floats) ----
    float Zs = 0.f;
#pragma unroll
    for (int j = 0; j < MAXJE; ++j) {
      const float s2 = xv[j] * a0L + e2a1L;
      const float p = exp2f(fmaxf(s2, ALPHAq * s2) - mx2);
      xv[j] = p;
      Zs += p;
    }
    for (int pos = tail0; pos < p1; pos += 4) {
      const float s2 = xnl[(int)g_nodes[pos]] * a0L + e2a1L;
      Zs += exp2f(fmaxf(s2, ALPHAq * s2) - mx2);
    }
    Zs += qswap1(Zs);
    Zs += qswap2(Zs);
    const float we = edge2 / Zs;

    // ---- write attn*edge into padded node-major wvl (sentinels -> dump, write 0) ----
#pragma unroll
    for (int j = 0; j < MAXJE; ++j)
      wvl[uj[j] >> 16] = xv[j] * we;
    for (int pos = tail0; pos < p1; pos += 4) {
      const float s2 = xnl[(int)g_nodes[pos]] * a0L + e2a1L;
      wvl[(int)wpos_g[pos]] = exp2f(fmaxf(s2, ALPHAq * s2) - mx2) * we;
    }
    __syncthreads();  // S2: wvl complete

    // ---- node side: b128 sums over my padded run; node0 via wave-0 reduce ----
    float nv = 0.f;
    if (tid < 64) {                             // wvl[0..255] = node0's slots
      const float4 w4 = reinterpret_cast<const float4*>(wvl)[tid];
      float q = w4.x + w4.y + w4.z + w4.w;
#pragma unroll
      for (int m = 32; m > 0; m >>= 1) q += __shfl_xor(q, m);
      if (tid == 0) nv = q;
    }
    for (int i = 0; i < iters; ++i) {
      const float4 w4 = reinterpret_cast<const float4*>(wvl)[q0v + i];
      nv += w4.x + w4.y + w4.z + w4.w;          // pad slots are exactly 0
    }

    // ---- epilogue: write out, advance xn ----
    out[((size_t)b * Tq + t) * Nq + tid] = nv;
    xn_reg = xnext + w32 * nv;
    xnl[tid] = xn_reg;
    __syncthreads();  // S3: xnl ready for next step
  }
}

extern "C" void kernel_launch(void* const* d_in, const int* in_sizes, int n_in,
                              void* d_out, int out_size, void* d_ws, size_t ws_size,
                              hipStream_t stream) {
  (void)in_sizes; (void)n_in; (void)out_size; (void)ws_size;
  const float* x      = (const float*)d_in[0];
  const float* mask   = (const float*)d_in[1];
  const float* inc    = (const float*)d_in[2];
  const float* h0     = (const float*)d_in[3];
  const float* bias   = (const float*)d_in[5];
  const float* weight = (const float*)d_in[6];
  const float* w2     = (const float*)d_in[7];
  const float* avec   = (const float*)d_in[8];
  float* out = (float*)d_out;

  char* ws = (char*)d_ws;
  size_t off = 0;
  auto alloc = [&](size_t bytes) { void* p = ws + off; off += (bytes + 255) & ~(size_t)255; return p; };
  int*            g_ptr   = (int*)alloc((Eq + 1) * 4);
  int*            gcnt    = (int*)alloc(16 * Eq * 4);
  int*            goff    = (int*)alloc(16 * Eq * 4);
  unsigned short* g_nodes = (unsigned short*)alloc((size_t)NNZCAP * 2);
  int*            ncnt    = (int*)alloc(Nq * 4);
  int*            tlp_g   = (int*)alloc((Nq + 1) * 4);
  int*            tlp2_g  = (int*)alloc((Nq + 1) * 4);
  unsigned short* tle_g   = (unsigned short*)alloc((size_t)NNZCAP * 2);
  unsigned short* wpos_g  = (unsigned short*)alloc((size_t)NNZCAP * 2);
  unsigned*       tbl_g   = (unsigned*)alloc((size_t)MAXJE * Nq * 4);
  float*          xnpT    = (float*)alloc((size_t)Bq * Tq * Nq * 4);

  k_cntB <<<16, 256, 0, stream>>>(inc, gcnt, ncnt);
  k_prefB<<<1, 1024, 0, stream>>>(gcnt, ncnt, g_ptr, goff, tlp_g, tlp2_g);
  k_fillB<<<16, 256, 0, stream>>>(inc, goff, tlp_g, g_nodes, tle_g);
  k_prep <<<4, 256, 0, stream>>>(g_ptr, g_nodes, tlp_g, tlp2_g, tle_g, tbl_g, wpos_g);
  k_xnp  <<<128, 256, 0, stream>>>(x, mask, weight, bias, xnpT);
  k_recur<<<Bq, 1024, 0, stream>>>(xnpT, w2, g_ptr, g_nodes, wpos_g, tlp_g, tlp2_g,
                                   tbl_g, h0, weight, avec, out);
}

// Round 15
// 538.014 us; speedup vs baseline: 1.0974x; 1.0974x over previous
//
#include <hip/hip_runtime.h>

#define Bq 8
#define Fq 16
#define Nq 1024
#define Eq 256
#define Tq 64
constexpr float ALPHAq = 0.2f;
constexpr float LOG2Eq = 1.4426950408889634f;
constexpr int NNZCAP = 32768;       // global CSR allocation cap (actual nnz ~13.4K)
constexpr int MAXJE  = 20;          // edge-side entries/thread in regs (deg<=80); tail covers rest
constexpr int NNZW2  = 20480;       // padded node-major wvl data slots (actual ~15K)
constexpr int DUMP0  = NNZW2;       // 1024 dump slots for sentinel writes
constexpr int WVLTOT = NNZW2 + 1024;

// raw v_exp_f32 (base-2 exp), no OCML denormal fixup (round-14 lesson: libm
// exp2f lowers to the strict OCML path and cost more VALU than it saved).
__device__ __forceinline__ float fast_exp2(float x) {
  return __builtin_amdgcn_exp2f(x);
}

// quad-lane exchanges on the VALU pipe (DPP), replacing ds_bpermute shuffles.
// quad_perm [1,0,3,2] = 0xB1 (lane^1), [2,3,0,1] = 0x4E (lane^2).
__device__ __forceinline__ float qswap1(float x) {
  return __int_as_float(__builtin_amdgcn_mov_dpp(__float_as_int(x), 0xB1, 0xF, 0xF, true));
}
__device__ __forceinline__ float qswap2(float x) {
  return __int_as_float(__builtin_amdgcn_mov_dpp(__float_as_int(x), 0x4E, 0xF, 0xF, true));
}

// ---------- counts: edge counts per rowblock + node counts ----------
__global__ __launch_bounds__(256) void k_cntB(const float* __restrict__ inc,
                                              int* __restrict__ gcnt,
                                              int* __restrict__ ncnt) {
  const int i = blockIdx.x, e = threadIdx.x;
  const int base = i * 64;
  int c = 0;
  for (int r = 0; r < 64; ++r) c += (inc[(size_t)(base + r) * Eq + e] > 0.f) ? 1 : 0;
  gcnt[i * Eq + e] = c;
  if (i < 4) {
    const int n = i * 256 + e;
    const float* row = inc + (size_t)n * Eq;
    int cn = 0;
    for (int k = 0; k < Eq; ++k) cn += (row[k] > 0.f) ? 1 : 0;
    ncnt[n] = cn;
  }
}

// ---------- prefixes: edge CSR ptr + rowblock offsets + node CSR (plain & padded) ----------
__global__ __launch_bounds__(1024) void k_prefB(const int* __restrict__ gcnt,
                                                const int* __restrict__ ncnt,
                                                int* __restrict__ g_ptr,
                                                int* __restrict__ goff,
                                                int* __restrict__ tlp,
                                                int* __restrict__ tlp2) {
  __shared__ int tot[Eq];
  __shared__ int sptr[Eq + 1];
  __shared__ int sn[Nq];
  __shared__ int snp[Nq + 1];
  __shared__ int snp2[Nq + 1];
  const int tid = threadIdx.x;
  if (tid < Eq) { int s = 0; for (int i = 0; i < 16; ++i) s += gcnt[i * Eq + tid]; tot[tid] = s; }
  sn[tid] = ncnt[tid];
  __syncthreads();
  if (tid == 0) { int s = 0; for (int j = 0; j < Eq; ++j) { sptr[j] = s; s += tot[j]; } sptr[Eq] = s; }
  if (tid == 1) { int s = 0; for (int i = 0; i < Nq; ++i) { snp[i] = s; s += sn[i]; } snp[Nq] = s; }
  if (tid == 2) { int s = 0; for (int i = 0; i < Nq; ++i) { snp2[i] = s; s += (sn[i] + 3) & ~3; } snp2[Nq] = s; }
  __syncthreads();
  if (tid <= Eq) g_ptr[tid] = sptr[tid];
  tlp[tid] = snp[tid];
  tlp2[tid] = snp2[tid];
  if (tid == 0) { tlp[Nq] = snp[Nq]; tlp2[Nq] = snp2[Nq]; }
  if (tid < Eq) {
    int run = sptr[tid];
    for (int i = 0; i < 16; ++i) { goff[i * Eq + tid] = run; run += gcnt[i * Eq + tid]; }
  }
}

// ---------- fills: edge-CSR node list + node-CSR edge list ----------
__global__ __launch_bounds__(256) void k_fillB(const float* __restrict__ inc,
                                               const int* __restrict__ goff,
                                               const int* __restrict__ tlp,
                                               unsigned short* __restrict__ g_nodes,
                                               unsigned short* __restrict__ tle_g) {
  const int i = blockIdx.x, e = threadIdx.x;
  const int base = i * 64;
  int w = goff[i * Eq + e];
  for (int r = 0; r < 64; ++r) {
    const int n = base + r;
    if (inc[(size_t)n * Eq + e] > 0.f) { if (w < NNZCAP) g_nodes[w] = (unsigned short)n; ++w; }
  }
  if (i < 4) {
    const int n = i * 256 + e;
    const float* row = inc + (size_t)n * Eq;
    int wn = tlp[n];
    for (int k = 0; k < Eq; ++k)
      if (row[k] > 0.f) { if (wn < NNZCAP) tle_g[wn] = (unsigned short)k; ++wn; }
  }
}

// ---------- prep: packed (wpos2<<16 | n) per-thread table + padded wpos map ----------
__global__ __launch_bounds__(256) void k_prep(const int* __restrict__ g_ptr,
                                              const unsigned short* __restrict__ g_nodes,
                                              const int* __restrict__ tlp_g,
                                              const int* __restrict__ tlp2_g,
                                              const unsigned short* __restrict__ tle_g,
                                              unsigned* __restrict__ tbl_g,
                                              unsigned short* __restrict__ wpos_g) {
  const int t = blockIdx.x * 256 + threadIdx.x;   // 0..1023 (e = t>>2, sub = t&3)
  const int e = t >> 2, sub = t & 3;
  const int p0 = g_ptr[e], p1 = g_ptr[e + 1];
  int j = 0;
  for (int pos = p0 + sub; pos < p1; pos += 4, ++j) {
    const int n = (int)g_nodes[pos];
    int lo = tlp_g[n], hi = tlp_g[n + 1];
    while (lo < hi) { int mid = (lo + hi) >> 1; if ((int)tle_g[mid] < e) lo = mid + 1; else hi = mid; }
    int wp = tlp2_g[n] + (lo - tlp_g[n]);          // padded node-major slot
    if (wp >= NNZW2) wp = DUMP0 + t;               // defensive clamp
    wpos_g[pos] = (unsigned short)wp;
    if (j < MAXJE) tbl_g[j * Nq + t] = ((unsigned)wp << 16) | (unsigned)n;
  }
  for (; j < MAXJE; ++j)
    tbl_g[j * Nq + t] = ((unsigned)(DUMP0 + t) << 16) | (unsigned)Nq;   // sentinel
}

// ---------- static node projection for all timesteps ----------
__global__ __launch_bounds__(256) void k_xnp(const float* __restrict__ x,
                                             const float* __restrict__ mask,
                                             const float* __restrict__ weight,
                                             const float* __restrict__ bias,
                                             float* __restrict__ xnpT) {
  __shared__ float accs[64][65];
  const int wg = blockIdx.x;
  const int b = wg >> 4;
  const int n0 = (wg & 15) << 6;
  const int lane = threadIdx.x & 63;
  const int w = threadIdx.x >> 6;
  float a[16];
#pragma unroll
  for (int i = 0; i < 16; ++i) a[i] = 0.f;
  for (int f = 0; f < Fq; ++f) {
    const float wf = weight[f], wm = weight[Fq + f];
#pragma unroll
    for (int ii = 0; ii < 16; ++ii) {
      const int i = w + ii * 4;
      const size_t base = ((size_t)(b * Fq + f) * Nq + n0 + i) * Tq + lane;
      a[ii] += x[base] * wf + mask[base] * wm;
    }
  }
#pragma unroll
  for (int ii = 0; ii < 16; ++ii) accs[w + ii * 4][lane] = a[ii];
  __syncthreads();
  const float bl = bias[n0 + lane];
#pragma unroll
  for (int jj = 0; jj < 16; ++jj) {
    const int tt = w + jj * 4;
    xnpT[((size_t)b * Tq + tt) * Nq + n0 + lane] = accs[lane][tt] + bl;
  }
}

// ---------- full 64-step recurrence: one block per batch ----------
// Round-12 structure; exp in base-2 domain via RAW v_exp_f32 (builtin), with
// log2e folded into constants (a0L, e2a1L). Correlated rounding: s2 and sm2
// share the same expression, so the max entry's arg == 0 exactly, all <= 0.
__global__ __attribute__((amdgpu_flat_work_group_size(1024, 1024), amdgpu_waves_per_eu(4, 4)))
void k_recur(
    const float* __restrict__ xnpT, const float* __restrict__ w2,
    const int* __restrict__ g_ptr, const unsigned short* __restrict__ g_nodes,
    const unsigned short* __restrict__ wpos_g,
    const int* __restrict__ tlp_g, const int* __restrict__ tlp2_g,
    const unsigned* __restrict__ tbl_g,
    const float* __restrict__ h0,
    const float* __restrict__ weight, const float* __restrict__ a_vec,
    float* __restrict__ out) {
  __shared__ __align__(16) float wvl[WVLTOT];   // 86KB padded node-major attn*edge (+dump)
  __shared__ float xnl[Nq + 4];                 // xn this step; [1024] = 0 sentinel
  __shared__ __align__(16) float epp[4 * 72];   // edge_pre, bank-padded (stride 72)

  const int b = blockIdx.x;
  const int tid = threadIdx.x;
  const int e = tid >> 2;                       // 256 edges, 4 threads each
  const int sub = tid & 3;
  const float w32 = weight[2 * Fq];
  const float a0 = a_vec[0], a1 = a_vec[1];
  const float a0L = a0 * LOG2Eq;                // base-2-domain slope

  // ---- zero wvl once (pads stay 0 forever; real slots rewritten every step) ----
  for (int i = tid; i < WVLTOT; i += 1024) wvl[i] = 0.f;

  float xn_reg = xnpT[(size_t)b * Tq * Nq + tid] + w32 * h0[tid];
  xnl[tid] = xn_reg;
  if (tid == 0) xnl[Nq] = 0.f;                  // pass1 sentinel

  // ---- constant per-thread index table in registers ----
  unsigned uj[MAXJE];
#pragma unroll
  for (int j = 0; j < MAXJE; ++j) uj[j] = tbl_g[j * Nq + tid];

  // ---- w2 column slice in registers: w2r[kk] = w2[sub*64+kk][e] ----
  float w2r[64];
#pragma unroll
  for (int kk = 0; kk < 64; ++kk)
    w2r[kk] = w2[(size_t)(sub * 64 + kk) * Eq + e];

  const int p0 = g_ptr[e], p1 = g_ptr[e + 1];
  const float degf = (float)(p1 - p0);
  const int tail0 = p0 + sub + 4 * MAXJE;       // edge-side tail start (deg>80 only)
  const int q0v = tlp2_g[tid] >> 2;             // my node's first float4 slot
  const int degn = tlp_g[tid + 1] - tlp_g[tid];
  const int iters = (tid == 0) ? 0 : ((degn + 3) >> 2);   // node0 via wave-0 reduce
  __syncthreads();                              // xnl + wvl zeros ready

  float xv[MAXJE];

  for (int t = 0; t < Tq; ++t) {
    // prefetch next xnp row value for my node
    const float xnext = xnpT[((size_t)b * Tq + (t + 1 < Tq ? t + 1 : t)) * Nq + tid];

    // ---- pass1: gather incident xn; edge_pre partial; running max (monotonicity) ----
    float v = 0.f;
    float mxv = -3.0e38f;
#pragma unroll
    for (int j = 0; j < MAXJE; ++j) {
      const int n = (int)(uj[j] & 0xffffu);
      const float xx = xnl[n];                  // sentinel n=1024 -> 0
      v += xx;
      const float val = (n < Nq) ? xx : -1.0e30f;
      xv[j] = val;
      mxv = fmaxf(mxv, val);
    }
    for (int pos = tail0; pos < p1; pos += 4) {
      const float xx = xnl[(int)g_nodes[pos]];
      v += xx;
      mxv = fmaxf(mxv, xx);
    }
    v += qswap1(v);
    v += qswap2(v);
    mxv = fmaxf(mxv, qswap1(mxv));
    mxv = fmaxf(mxv, qswap2(mxv));
    if (sub == 0) epp[(e >> 6) * 72 + (e & 63)] = v / degf;
    __syncthreads();  // S1: ep complete

    // ---- mat-vec: edge2 = ep @ w2 (register w2, bank-padded b128 ep reads) ----
    float acc = 0.f;
#pragma unroll
    for (int k = 0; k < 16; ++k) {
      const float4 epv = *reinterpret_cast<const float4*>(&epp[sub * 72 + (k << 2)]);
      acc += w2r[k * 4 + 0] * epv.x + w2r[k * 4 + 1] * epv.y +
             w2r[k * 4 + 2] * epv.z + w2r[k * 4 + 3] * epv.w;
    }
    acc += qswap1(acc);
    acc += qswap2(acc);
    const float edge2 = acc;                    // time_e cancels in the softmax ratio
    // base-2 domain: everything scaled by log2e via the constants
    const float e2a1L = (edge2 * a1) * LOG2Eq;
    // max via monotonicity; SAME expression shape as per-entry s2
    const float sm2 = mxv * a0L + e2a1L;
    const float mx2 = fmaxf(sm2, ALPHAq * sm2);

    // ---- Z; overwrite xv with exp2 (correlated rounding: arg <= 0 in floats) ----
    float Zs = 0.f;
#pragma unroll
    for (int j = 0; j < MAXJE; ++j) {
      const float s2 = xv[j] * a0L + e2a1L;
      const float p = fast_exp2(fmaxf(s2, ALPHAq * s2) - mx2);
      xv[j] = p;
      Zs += p;
    }
    for (int pos = tail0; pos < p1; pos += 4) {
      const float s2 = xnl[(int)g_nodes[pos]] * a0L + e2a1L;
      Zs += fast_exp2(fmaxf(s2, ALPHAq * s2) - mx2);
    }
    Zs += qswap1(Zs);
    Zs += qswap2(Zs);
    const float we = edge2 / Zs;

    // ---- write attn*edge into padded node-major wvl (sentinels -> dump, write 0) ----
#pragma unroll
    for (int j = 0; j < MAXJE; ++j)
      wvl[uj[j] >> 16] = xv[j] * we;
    for (int pos = tail0; pos < p1; pos += 4) {
      const float s2 = xnl[(int)g_nodes[pos]] * a0L + e2a1L;
      wvl[(int)wpos_g[pos]] = fast_exp2(fmaxf(s2, ALPHAq * s2) - mx2) * we;
    }
    __syncthreads();  // S2: wvl complete

    // ---- node side: b128 sums over my padded run; node0 via wave-0 reduce ----
    float nv = 0.f;
    if (tid < 64) {                             // wvl[0..255] = node0's slots
      const float4 w4 = reinterpret_cast<const float4*>(wvl)[tid];
      float q = w4.x + w4.y + w4.z + w4.w;
#pragma unroll
      for (int m = 32; m > 0; m >>= 1) q += __shfl_xor(q, m);
      if (tid == 0) nv = q;
    }
    for (int i = 0; i < iters; ++i) {
      const float4 w4 = reinterpret_cast<const float4*>(wvl)[q0v + i];
      nv += w4.x + w4.y + w4.z + w4.w;          // pad slots are exactly 0
    }

    // ---- epilogue: write out, advance xn ----
    out[((size_t)b * Tq + t) * Nq + tid] = nv;
    xn_reg = xnext + w32 * nv;
    xnl[tid] = xn_reg;
    __syncthreads();  // S3: xnl ready for next step
  }
}

extern "C" void kernel_launch(void* const* d_in, const int* in_sizes, int n_in,
                              void* d_out, int out_size, void* d_ws, size_t ws_size,
                              hipStream_t stream) {
  (void)in_sizes; (void)n_in; (void)out_size; (void)ws_size;
  const float* x      = (const float*)d_in[0];
  const float* mask   = (const float*)d_in[1];
  const float* inc    = (const float*)d_in[2];
  const float* h0     = (const float*)d_in[3];
  const float* bias   = (const float*)d_in[5];
  const float* weight = (const float*)d_in[6];
  const float* w2     = (const float*)d_in[7];
  const float* avec   = (const float*)d_in[8];
  float* out = (float*)d_out;

  char* ws = (char*)d_ws;
  size_t off = 0;
  auto alloc = [&](size_t bytes) { void* p = ws + off; off += (bytes + 255) & ~(size_t)255; return p; };
  int*            g_ptr   = (int*)alloc((Eq + 1) * 4);
  int*            gcnt    = (int*)alloc(16 * Eq * 4);
  int*            goff    = (int*)alloc(16 * Eq * 4);
  unsigned short* g_nodes = (unsigned short*)alloc((size_t)NNZCAP * 2);
  int*            ncnt    = (int*)alloc(Nq * 4);
  int*            tlp_g   = (int*)alloc((Nq + 1) * 4);
  int*            tlp2_g  = (int*)alloc((Nq + 1) * 4);
  unsigned short* tle_g   = (unsigned short*)alloc((size_t)NNZCAP * 2);
  unsigned short* wpos_g  = (unsigned short*)alloc((size_t)NNZCAP * 2);
  unsigned*       tbl_g   = (unsigned*)alloc((size_t)MAXJE * Nq * 4);
  float*          xnpT    = (float*)alloc((size_t)Bq * Tq * Nq * 4);

  k_cntB <<<16, 256, 0, stream>>>(inc, gcnt, ncnt);
  k_prefB<<<1, 1024, 0, stream>>>(gcnt, ncnt, g_ptr, goff, tlp_g, tlp2_g);
  k_fillB<<<16, 256, 0, stream>>>(inc, goff, tlp_g, g_nodes, tle_g);
  k_prep <<<4, 256, 0, stream>>>(g_ptr, g_nodes, tlp_g, tlp2_g, tle_g, tbl_g, wpos_g);
  k_xnp  <<<128, 256, 0, stream>>>(x, mask, weight, bias, xnpT);
  k_recur<<<Bq, 1024, 0, stream>>>(xnpT, w2, g_ptr, g_nodes, wpos_g, tlp_g, tlp2_g,
                                   tbl_g, h0, weight, avec, out);
}

// Round 16
// 467.028 us; speedup vs baseline: 1.2642x; 1.1520x over previous
//
#include <hip/hip_runtime.h>

#define Bq 8
#define Fq 16
#define Nq 1024
#define Eq 256
#define Tq 64
constexpr float ALPHAq = 0.2f;
constexpr float LOG2Eq = 1.4426950408889634f;
constexpr int NNZCAP = 32768;       // global CSR allocation cap (actual nnz ~13.4K)
constexpr int MAXJE  = 20;          // edge-side entries/thread in regs (deg<=80); tail covers rest
constexpr int NNZW2  = 20480;       // padded node-major wvl data slots (actual ~15K)
constexpr int DUMP0  = NNZW2;       // 1024 dump slots for sentinel writes
constexpr int WVLTOT = NNZW2 + 1024;

// raw v_exp_f32 (base-2 exp), no OCML denormal fixup (round-14 lesson).
__device__ __forceinline__ float fast_exp2(float x) {
  return __builtin_amdgcn_exp2f(x);
}

// quad-lane exchanges on the VALU pipe (DPP).
__device__ __forceinline__ float qswap1(float x) {
  return __int_as_float(__builtin_amdgcn_mov_dpp(__float_as_int(x), 0xB1, 0xF, 0xF, true));
}
__device__ __forceinline__ float qswap2(float x) {
  return __int_as_float(__builtin_amdgcn_mov_dpp(__float_as_int(x), 0x4E, 0xF, 0xF, true));
}

// parallel exclusive scan over 1024 values (Hillis-Steele in LDS); also returns total
__device__ __forceinline__ int scan_excl_1024(int* s, int tid, int val, int* total) {
  __syncthreads();                  // protect s reuse across calls
  s[tid] = val;
  __syncthreads();
  for (int d = 1; d < 1024; d <<= 1) {
    int t = s[tid];
    if (tid >= d) t += s[tid - d];
    __syncthreads();
    s[tid] = t;
    __syncthreads();
  }
  *total = s[1023];
  return s[tid] - val;
}

// ---------- counts: edge counts per rowblock + node counts (coalesced) ----------
__global__ __launch_bounds__(256) void k_cntB(const float* __restrict__ inc,
                                              int* __restrict__ gcnt,
                                              int* __restrict__ ncnt) {
  __shared__ int cp[64][4];
  const int i = blockIdx.x, tid = threadIdx.x;
  // edge counts: thread e scans 64 rows (coalesced across e)
  {
    const int e = tid, base = i * 64;
    int c = 0;
    for (int r = 0; r < 64; ++r) c += (inc[(size_t)(base + r) * Eq + e] > 0.f) ? 1 : 0;
    gcnt[i * Eq + e] = c;
  }
  // node counts: 64 nodes x 4 chunks per block, float4 reads
  const int nl = tid >> 2, kc = tid & 3, n = i * 64 + nl;
  {
    const float4* r4 = (const float4*)(inc + (size_t)n * Eq + kc * 64);
    int c = 0;
    for (int j = 0; j < 16; ++j) {
      const float4 v = r4[j];
      c += (v.x > 0.f) + (v.y > 0.f) + (v.z > 0.f) + (v.w > 0.f);
    }
    cp[nl][kc] = c;
  }
  __syncthreads();
  if (kc == 0) ncnt[n] = cp[nl][0] + cp[nl][1] + cp[nl][2] + cp[nl][3];
}

// ---------- prefixes: parallel scans (edge CSR ptr + rowblock offsets + node CSR) ----------
__global__ __launch_bounds__(1024) void k_prefB(const int* __restrict__ gcnt,
                                                const int* __restrict__ ncnt,
                                                int* __restrict__ g_ptr,
                                                int* __restrict__ goff,
                                                int* __restrict__ tlp,
                                                int* __restrict__ tlp2) {
  __shared__ int s[1024];
  const int tid = threadIdx.x;
  int tot;
  // edge scan (padded to 1024 with zeros)
  int tote = 0;
  if (tid < Eq) for (int i = 0; i < 16; ++i) tote += gcnt[i * Eq + tid];
  const int exE = scan_excl_1024(s, tid, (tid < Eq) ? tote : 0, &tot);
  if (tid < Eq) {
    g_ptr[tid] = exE;
    int run = exE;
    for (int i = 0; i < 16; ++i) { goff[i * Eq + tid] = run; run += gcnt[i * Eq + tid]; }
  }
  if (tid == 0) g_ptr[Eq] = tot;
  // node scans (plain + padded)
  const int dn = ncnt[tid];
  const int exN = scan_excl_1024(s, tid, dn, &tot);
  tlp[tid] = exN;
  if (tid == 0) tlp[Nq] = tot;
  const int dp = (dn + 3) & ~3;
  const int exP = scan_excl_1024(s, tid, dp, &tot);
  tlp2[tid] = exP;
  if (tid == 0) tlp2[Nq] = tot;
}

// ---------- fills: edge-CSR node list + node-side rank8 map ----------
// rank8[n*256+e] = rank of edge e among node n's incident edges (ascending e).
// Max rank 255 (node0 has deg 256) fits u8 exactly.
__global__ __launch_bounds__(256) void k_fillB(const float* __restrict__ inc,
                                               const int* __restrict__ goff,
                                               unsigned short* __restrict__ g_nodes,
                                               unsigned char* __restrict__ rank8) {
  __shared__ int cp[64][4];
  const int i = blockIdx.x, tid = threadIdx.x;
  // edge-CSR fill (ascending n per edge; entry0 = node0)
  {
    const int e = tid, base = i * 64;
    int w = goff[i * Eq + e];
    for (int r = 0; r < 64; ++r) {
      const int n = base + r;
      if (inc[(size_t)n * Eq + e] > 0.f) { if (w < NNZCAP) g_nodes[w] = (unsigned short)n; ++w; }
    }
  }
  // node-side rank map: 64 nodes x 4 chunks per block
  const int nl = tid >> 2, kc = tid & 3, n = i * 64 + nl;
  const float* row = inc + (size_t)n * Eq + kc * 64;
  {
    const float4* r4 = (const float4*)row;
    int c = 0;
    for (int j = 0; j < 16; ++j) {
      const float4 v = r4[j];
      c += (v.x > 0.f) + (v.y > 0.f) + (v.z > 0.f) + (v.w > 0.f);
    }
    cp[nl][kc] = c;
  }
  __syncthreads();
  {
    int base = 0;
    for (int c2 = 0; c2 < kc; ++c2) base += cp[nl][c2];
    int r = base;
    for (int k = 0; k < 64; ++k)
      if (row[k] > 0.f) { rank8[(size_t)n * Eq + kc * 64 + k] = (unsigned char)r; ++r; }
  }
}

// ---------- prep: packed (wpos2<<16 | n) per-thread table + padded wpos map ----------
// wpos = tlp2[n] + rank8[n][e] -- direct lookup, no binary search (round-16 change).
__global__ __launch_bounds__(256) void k_prep(const int* __restrict__ g_ptr,
                                              const unsigned short* __restrict__ g_nodes,
                                              const int* __restrict__ tlp2_g,
                                              const unsigned char* __restrict__ rank8,
                                              unsigned* __restrict__ tbl_g,
                                              unsigned short* __restrict__ wpos_g) {
  const int t = blockIdx.x * 256 + threadIdx.x;   // 0..1023 (e = t>>2, sub = t&3)
  const int e = t >> 2, sub = t & 3;
  const int p0 = g_ptr[e], p1 = g_ptr[e + 1];
  int j = 0;
  for (int pos = p0 + sub; pos < p1; pos += 4, ++j) {
    const int n = (int)g_nodes[pos];
    int wp = tlp2_g[n] + (int)rank8[(size_t)n * Eq + e];
    if (wp >= NNZW2) wp = DUMP0 + t;               // defensive clamp
    wpos_g[pos] = (unsigned short)wp;
    if (j < MAXJE) tbl_g[j * Nq + t] = ((unsigned)wp << 16) | (unsigned)n;
  }
  for (; j < MAXJE; ++j)
    tbl_g[j * Nq + t] = ((unsigned)(DUMP0 + t) << 16) | (unsigned)Nq;   // sentinel
}

// ---------- static node projection for all timesteps ----------
__global__ __launch_bounds__(256) void k_xnp(const float* __restrict__ x,
                                             const float* __restrict__ mask,
                                             const float* __restrict__ weight,
                                             const float* __restrict__ bias,
                                             float* __restrict__ xnpT) {
  __shared__ float accs[64][65];
  const int wg = blockIdx.x;
  const int b = wg >> 4;
  const int n0 = (wg & 15) << 6;
  const int lane = threadIdx.x & 63;
  const int w = threadIdx.x >> 6;
  float a[16];
#pragma unroll
  for (int i = 0; i < 16; ++i) a[i] = 0.f;
  for (int f = 0; f < Fq; ++f) {
    const float wf = weight[f], wm = weight[Fq + f];
#pragma unroll
    for (int ii = 0; ii < 16; ++ii) {
      const int i = w + ii * 4;
      const size_t base = ((size_t)(b * Fq + f) * Nq + n0 + i) * Tq + lane;
      a[ii] += x[base] * wf + mask[base] * wm;
    }
  }
#pragma unroll
  for (int ii = 0; ii < 16; ++ii) accs[w + ii * 4][lane] = a[ii];
  __syncthreads();
  const float bl = bias[n0 + lane];
#pragma unroll
  for (int jj = 0; jj < 16; ++jj) {
    const int tt = w + jj * 4;
    xnpT[((size_t)b * Tq + tt) * Nq + n0 + lane] = accs[lane][tt] + bl;
  }
}

// ---------- full 64-step recurrence: one block per batch (UNCHANGED from round 15) ----------
__global__ __attribute__((amdgpu_flat_work_group_size(1024, 1024), amdgpu_waves_per_eu(4, 4)))
void k_recur(
    const float* __restrict__ xnpT, const float* __restrict__ w2,
    const int* __restrict__ g_ptr, const unsigned short* __restrict__ g_nodes,
    const unsigned short* __restrict__ wpos_g,
    const int* __restrict__ tlp_g, const int* __restrict__ tlp2_g,
    const unsigned* __restrict__ tbl_g,
    const float* __restrict__ h0,
    const float* __restrict__ weight, const float* __restrict__ a_vec,
    float* __restrict__ out) {
  __shared__ __align__(16) float wvl[WVLTOT];   // 86KB padded node-major attn*edge (+dump)
  __shared__ float xnl[Nq + 4];                 // xn this step; [1024] = 0 sentinel
  __shared__ __align__(16) float epp[4 * 72];   // edge_pre, bank-padded (stride 72)

  const int b = blockIdx.x;
  const int tid = threadIdx.x;
  const int e = tid >> 2;                       // 256 edges, 4 threads each
  const int sub = tid & 3;
  const float w32 = weight[2 * Fq];
  const float a0 = a_vec[0], a1 = a_vec[1];
  const float a0L = a0 * LOG2Eq;                // base-2-domain slope

  for (int i = tid; i < WVLTOT; i += 1024) wvl[i] = 0.f;

  float xn_reg = xnpT[(size_t)b * Tq * Nq + tid] + w32 * h0[tid];
  xnl[tid] = xn_reg;
  if (tid == 0) xnl[Nq] = 0.f;                  // pass1 sentinel

  unsigned uj[MAXJE];
#pragma unroll
  for (int j = 0; j < MAXJE; ++j) uj[j] = tbl_g[j * Nq + tid];

  float w2r[64];
#pragma unroll
  for (int kk = 0; kk < 64; ++kk)
    w2r[kk] = w2[(size_t)(sub * 64 + kk) * Eq + e];

  const int p0 = g_ptr[e], p1 = g_ptr[e + 1];
  const float degf = (float)(p1 - p0);
  const int tail0 = p0 + sub + 4 * MAXJE;       // edge-side tail start (deg>80 only)
  const int q0v = tlp2_g[tid] >> 2;             // my node's first float4 slot
  const int degn = tlp_g[tid + 1] - tlp_g[tid];
  const int iters = (tid == 0) ? 0 : ((degn + 3) >> 2);   // node0 via wave-0 reduce
  __syncthreads();                              // xnl + wvl zeros ready

  float xv[MAXJE];

  for (int t = 0; t < Tq; ++t) {
    const float xnext = xnpT[((size_t)b * Tq + (t + 1 < Tq ? t + 1 : t)) * Nq + tid];

    // ---- pass1: gather incident xn; edge_pre partial; running max (monotonicity) ----
    float v = 0.f;
    float mxv = -3.0e38f;
#pragma unroll
    for (int j = 0; j < MAXJE; ++j) {
      const int n = (int)(uj[j] & 0xffffu);
      const float xx = xnl[n];                  // sentinel n=1024 -> 0
      v += xx;
      const float val = (n < Nq) ? xx : -1.0e30f;
      xv[j] = val;
      mxv = fmaxf(mxv, val);
    }
    for (int pos = tail0; pos < p1; pos += 4) {
      const float xx = xnl[(int)g_nodes[pos]];
      v += xx;
      mxv = fmaxf(mxv, xx);
    }
    v += qswap1(v);
    v += qswap2(v);
    mxv = fmaxf(mxv, qswap1(mxv));
    mxv = fmaxf(mxv, qswap2(mxv));
    if (sub == 0) epp[(e >> 6) * 72 + (e & 63)] = v / degf;
    __syncthreads();  // S1: ep complete

    // ---- mat-vec: edge2 = ep @ w2 (register w2, bank-padded b128 ep reads) ----
    float acc = 0.f;
#pragma unroll
    for (int k = 0; k < 16; ++k) {
      const float4 epv = *reinterpret_cast<const float4*>(&epp[sub * 72 + (k << 2)]);
      acc += w2r[k * 4 + 0] * epv.x + w2r[k * 4 + 1] * epv.y +
             w2r[k * 4 + 2] * epv.z + w2r[k * 4 + 3] * epv.w;
    }
    acc += qswap1(acc);
    acc += qswap2(acc);
    const float edge2 = acc;                    // time_e cancels in the softmax ratio
    const float e2a1L = (edge2 * a1) * LOG2Eq;
    const float sm2 = mxv * a0L + e2a1L;
    const float mx2 = fmaxf(sm2, ALPHAq * sm2);

    // ---- Z; overwrite xv with exp2 (correlated rounding: arg <= 0 in floats) ----
    float Zs = 0.f;
#pragma unroll
    for (int j = 0; j < MAXJE; ++j) {
      const float s2 = xv[j] * a0L + e2a1L;
      const float p = fast_exp2(fmaxf(s2, ALPHAq * s2) - mx2);
      xv[j] = p;
      Zs += p;
    }
    for (int pos = tail0; pos < p1; pos += 4) {
      const float s2 = xnl[(int)g_nodes[pos]] * a0L + e2a1L;
      Zs += fast_exp2(fmaxf(s2, ALPHAq * s2) - mx2);
    }
    Zs += qswap1(Zs);
    Zs += qswap2(Zs);
    const float we = edge2 / Zs;

    // ---- write attn*edge into padded node-major wvl (sentinels -> dump, write 0) ----
#pragma unroll
    for (int j = 0; j < MAXJE; ++j)
      wvl[uj[j] >> 16] = xv[j] * we;
    for (int pos = tail0; pos < p1; pos += 4) {
      const float s2 = xnl[(int)g_nodes[pos]] * a0L + e2a1L;
      wvl[(int)wpos_g[pos]] = fast_exp2(fmaxf(s2, ALPHAq * s2) - mx2) * we;
    }
    __syncthreads();  // S2: wvl complete

    // ---- node side: b128 sums over my padded run; node0 via wave-0 reduce ----
    float nv = 0.f;
    if (tid < 64) {                             // wvl[0..255] = node0's slots
      const float4 w4 = reinterpret_cast<const float4*>(wvl)[tid];
      float q = w4.x + w4.y + w4.z + w4.w;
#pragma unroll
      for (int m = 32; m > 0; m >>= 1) q += __shfl_xor(q, m);
      if (tid == 0) nv = q;
    }
    for (int i = 0; i < iters; ++i) {
      const float4 w4 = reinterpret_cast<const float4*>(wvl)[q0v + i];
      nv += w4.x + w4.y + w4.z + w4.w;          // pad slots are exactly 0
    }

    // ---- epilogue: write out, advance xn ----
    out[((size_t)b * Tq + t) * Nq + tid] = nv;
    xn_reg = xnext + w32 * nv;
    xnl[tid] = xn_reg;
    __syncthreads();  // S3: xnl ready for next step
  }
}

extern "C" void kernel_launch(void* const* d_in, const int* in_sizes, int n_in,
                              void* d_out, int out_size, void* d_ws, size_t ws_size,
                              hipStream_t stream) {
  (void)in_sizes; (void)n_in; (void)out_size; (void)ws_size;
  const float* x      = (const float*)d_in[0];
  const float* mask   = (const float*)d_in[1];
  const float* inc    = (const float*)d_in[2];
  const float* h0     = (const float*)d_in[3];
  const float* bias   = (const float*)d_in[5];
  const float* weight = (const float*)d_in[6];
  const float* w2     = (const float*)d_in[7];
  const float* avec   = (const float*)d_in[8];
  float* out = (float*)d_out;

  char* ws = (char*)d_ws;
  size_t off = 0;
  auto alloc = [&](size_t bytes) { void* p = ws + off; off += (bytes + 255) & ~(size_t)255; return p; };
  int*            g_ptr   = (int*)alloc((Eq + 1) * 4);
  int*            gcnt    = (int*)alloc(16 * Eq * 4);
  int*            goff    = (int*)alloc(16 * Eq * 4);
  unsigned short* g_nodes = (unsigned short*)alloc((size_t)NNZCAP * 2);
  int*            ncnt    = (int*)alloc(Nq * 4);
  int*            tlp_g   = (int*)alloc((Nq + 1) * 4);
  int*            tlp2_g  = (int*)alloc((Nq + 1) * 4);
  unsigned char*  rank8   = (unsigned char*)alloc((size_t)Nq * Eq);
  unsigned short* wpos_g  = (unsigned short*)alloc((size_t)NNZCAP * 2);
  unsigned*       tbl_g   = (unsigned*)alloc((size_t)MAXJE * Nq * 4);
  float*          xnpT    = (float*)alloc((size_t)Bq * Tq * Nq * 4);

  k_cntB <<<16, 256, 0, stream>>>(inc, gcnt, ncnt);
  k_prefB<<<1, 1024, 0, stream>>>(gcnt, ncnt, g_ptr, goff, tlp_g, tlp2_g);
  k_fillB<<<16, 256, 0, stream>>>(inc, goff, g_nodes, rank8);
  k_prep <<<4, 256, 0, stream>>>(g_ptr, g_nodes, tlp2_g, rank8, tbl_g, wpos_g);
  k_xnp  <<<128, 256, 0, stream>>>(x, mask, weight, bias, xnpT);
  k_recur<<<Bq, 1024, 0, stream>>>(xnpT, w2, g_ptr, g_nodes, wpos_g, tlp_g, tlp2_g,
                                   tbl_g, h0, weight, avec, out);
}